// Round 1
// baseline (3229.847 us; speedup 1.0000x reference)
//
#include <hip/hip_runtime.h>

// Quantum circuit simulator: 16 wires, 6 StronglyEntanglingLayers, batch 128.
// One workgroup per batch element; state (2^16 complex64 = 512 KiB) lives in
// the workspace; gates applied in-place with __syncthreads() between them.
// Wire w corresponds to bit (15 - w) of the state index (wire 0 = MSB).

#define NW      16
#define NSTATE  65536    // 2^16
#define NPAIR   32768    // 2^15
#define NQUAD   16384    // 2^14
#define NLAYERS 6
#define BLK     1024

__global__ __launch_bounds__(BLK)
void qsim_kernel(const float* __restrict__ x,   // (B, 16)
                 const float* __restrict__ w,   // (6, 16, 3)
                 float* __restrict__ out,       // (B, 16)
                 float2* __restrict__ psi_all)  // (B, 65536) workspace
{
    const int b   = blockIdx.x;
    const int tid = threadIdx.x;
    float2* psi = psi_all + (size_t)b * NSTATE;

    // ---- init |00...0> ----
    for (int s = tid; s < NSTATE; s += BLK)
        psi[s] = make_float2(s == 0 ? 1.0f : 0.0f, 0.0f);
    __syncthreads();

    // ---- generic in-place single-qubit complex 2x2 gate ----
    auto apply1q = [&](int wire,
                       float m00r, float m00i, float m01r, float m01i,
                       float m10r, float m10i, float m11r, float m11i) {
        const int bit    = 15 - wire;
        const int stride = 1 << bit;
        for (int p = tid; p < NPAIR; p += BLK) {
            int lo = p & (stride - 1);
            int hi = (p >> bit) << (bit + 1);
            int i0 = hi | lo;
            int i1 = i0 | stride;
            float2 a0 = psi[i0];
            float2 a1 = psi[i1];
            float2 r0, r1;
            r0.x = m00r*a0.x - m00i*a0.y + m01r*a1.x - m01i*a1.y;
            r0.y = m00r*a0.y + m00i*a0.x + m01r*a1.y + m01i*a1.x;
            r1.x = m10r*a0.x - m10i*a0.y + m11r*a1.x - m11i*a1.y;
            r1.y = m10r*a0.y + m10i*a0.x + m11r*a1.y + m11i*a1.x;
            psi[i0] = r0;
            psi[i1] = r1;
        }
        __syncthreads();
    };

    // ---- AngleEmbedding: RY(x_i) on wire i (real matrix [c,-s; s,c]) ----
    for (int wire = 0; wire < NW; ++wire) {
        float a = 0.5f * x[b * NW + wire];
        float c = cosf(a), s = sinf(a);
        apply1q(wire, c, 0.f, -s, 0.f,
                      s, 0.f,  c, 0.f);
    }

    // ---- StronglyEntanglingLayers ----
    for (int l = 0; l < NLAYERS; ++l) {
        // Rot(phi, theta, omega) = RZ(omega) RY(theta) RZ(phi) on each wire
        for (int wire = 0; wire < NW; ++wire) {
            const float* ww = w + ((l * NW + wire) * 3);
            float phi = ww[0], th = ww[1], om = ww[2];
            float ct = cosf(0.5f * th), st = sinf(0.5f * th);
            float ap = 0.5f * (phi + om), am = 0.5f * (phi - om);
            float cap = cosf(ap), sap = sinf(ap);
            float cam = cosf(am), sam = sinf(am);
            // m00 = e^{-i ap} ct = (cap - i sap) ct
            // m01 = -e^{+i am} st = (-cam - i sam) st
            // m10 = e^{-i am} st = (cam - i sam) st
            // m11 = e^{+i ap} ct = (cap + i sap) ct
            apply1q(wire,
                    cap * ct, -sap * ct,  -cam * st, -sam * st,
                    cam * st, -sam * st,   cap * ct,  sap * ct);
        }

        // ring of CNOTs: control i, target (i + r) % 16, r = (l % 15) + 1
        const int r = (l % (NW - 1)) + 1;
        for (int i = 0; i < NW; ++i) {
            const int cb = 15 - i;
            const int tb = 15 - ((i + r) % NW);
            const int b1 = (cb < tb) ? cb : tb;
            const int b2 = (cb < tb) ? tb : cb;
            const int cmask = 1 << cb;
            const int tmask = 1 << tb;
            // enumerate the 2^14 indices with control=1, target=0; swap with target=1
            for (int p = tid; p < NQUAD; p += BLK) {
                int lo  = p & ((1 << b1) - 1);
                int mid = (p >> b1) & ((1 << (b2 - 1 - b1)) - 1);
                int hi  = p >> (b2 - 1);
                int idx  = (hi << (b2 + 1)) | (mid << (b1 + 1)) | lo | cmask;
                int idx2 = idx | tmask;
                float2 t0 = psi[idx];
                float2 t1 = psi[idx2];
                psi[idx]  = t1;
                psi[idx2] = t0;
            }
            __syncthreads();
        }
    }

    // ---- expectations <Z_i> = sum_s |psi[s]|^2 * (bit_i(s)==0 ? +1 : -1) ----
    float z[NW];
#pragma unroll
    for (int i = 0; i < NW; ++i) z[i] = 0.0f;

    for (int s = tid; s < NSTATE; s += BLK) {
        float2 a = psi[s];
        float p = a.x * a.x + a.y * a.y;
#pragma unroll
        for (int i = 0; i < NW; ++i)
            z[i] += ((s >> (15 - i)) & 1) ? -p : p;
    }

    __shared__ float acc[NW];
    if (tid < NW) acc[tid] = 0.0f;
    __syncthreads();

#pragma unroll
    for (int i = 0; i < NW; ++i) {
        float v = z[i];
        // wave(64)-level reduction
        for (int off = 32; off > 0; off >>= 1)
            v += __shfl_down(v, off, 64);
        if ((tid & 63) == 0)
            atomicAdd(&acc[i], v);
    }
    __syncthreads();

    if (tid < NW)
        out[b * NW + tid] = acc[tid];
}

extern "C" void kernel_launch(void* const* d_in, const int* in_sizes, int n_in,
                              void* d_out, int out_size, void* d_ws, size_t ws_size,
                              hipStream_t stream) {
    const float* x = (const float*)d_in[0];   // (B, 16) float32
    const float* w = (const float*)d_in[1];   // (6, 16, 3) float32
    float* out = (float*)d_out;               // (B, 16) float32
    float2* psi = (float2*)d_ws;              // needs B * 65536 * 8 bytes (64 MiB @ B=128)

    const int batch = in_sizes[0] / NW;
    qsim_kernel<<<batch, BLK, 0, stream>>>(x, w, out, psi);
}

// Round 2
// 759.866 us; speedup vs baseline: 4.2505x; 4.2505x over previous
//
#include <hip/hip_runtime.h>

// 16-wire statevector sim, batch 128, gate-fused in LDS.
// State: psi[b][s], s = 16-bit index, wire w <-> bit (15-w).
// Each block stages a 2^14-amp chunk (128 KiB) in LDS (2 "fixed" bits choose
// the chunk) and applies all gates acting on the 14 local bits.
// Schedule (commutation-verified): per layer l (r=l+1):
//   P1(l): fixed bits avoid wires {0,1,r,r+1,17-r,18-r}:
//          H2(l-1) CNOTs, Rot_l{0,1,r,r+1}, CNOT(0,r),(1,1+r)
//   P2(l): fixed bits {15,14}: Rot_l{2..15}\{r,r+1}, then ring CNOTs not
//          touching wires 0,1 (ascending i)
//   P3:    H2(5) + Z-readout (no state write-back)
// P1(0) generates the AngleEmbedding product state directly (no init sweep).

#define NW      16
#define BLK     1024
#define CHUNK   16384      // 2^14 amps per chunk
#define NPAIRC  8192       // pairs per chunk
#define NQUADC  4096       // cnot swap-pairs per chunk

// insert 2 fixed bits (f1 > f2) valued from c into 14-bit u -> 16-bit s
__device__ __forceinline__ int expand14(int u, int f1, int f2, int c) {
    int low  = u & ((1 << f2) - 1);
    int mid  = (u >> f2) & ((1 << (f1 - 1 - f2)) - 1);
    int high = u >> (f1 - 1);
    return (high << (f1 + 1)) | (((c >> 1) & 1) << f1) |
           (mid << (f2 + 1)) | ((c & 1) << f2) | low;
}

// local (chunk) bit position of global bit g, given fixed bits f1 > f2
__device__ __forceinline__ int localbit(int g, int f1, int f2) {
    return g - (g > f1 ? 1 : 0) - (g > f2 ? 1 : 0);
}

__device__ __forceinline__ void c2x2(float2& a0, float2& a1,
                                     float2 m00, float2 m01,
                                     float2 m10, float2 m11) {
    float2 r0, r1;
    r0.x = m00.x*a0.x - m00.y*a0.y + m01.x*a1.x - m01.y*a1.y;
    r0.y = m00.x*a0.y + m00.y*a0.x + m01.x*a1.y + m01.y*a1.x;
    r1.x = m10.x*a0.x - m10.y*a0.y + m11.x*a1.x - m11.y*a1.y;
    r1.y = m10.x*a0.y + m10.y*a0.x + m11.x*a1.y + m11.y*a1.x;
    a0 = r0; a1 = r1;
}

__device__ __forceinline__ void rot_lds(float2* amp, int lb,
                                        float2 m00, float2 m01,
                                        float2 m10, float2 m11) {
    const int tid = threadIdx.x;
    const int stride = 1 << lb;
#pragma unroll
    for (int it = 0; it < NPAIRC / BLK; ++it) {
        int p  = tid + it * BLK;
        int lo = p & (stride - 1);
        int i0 = ((p >> lb) << (lb + 1)) | lo;
        int i1 = i0 | stride;
        float2 a0 = amp[i0], a1 = amp[i1];
        c2x2(a0, a1, m00, m01, m10, m11);
        amp[i0] = a0; amp[i1] = a1;
    }
    __syncthreads();
}

__device__ __forceinline__ void cnot_lds(float2* amp, int cb, int tb) {
    const int tid = threadIdx.x;
    const int b1 = cb < tb ? cb : tb;
    const int b2 = cb < tb ? tb : cb;
#pragma unroll
    for (int it = 0; it < NQUADC / BLK; ++it) {
        int q   = tid + it * BLK;
        int lo  = q & ((1 << b1) - 1);
        int mid = (q >> b1) & ((1 << (b2 - 1 - b1)) - 1);
        int hi  = q >> (b2 - 1);
        int idx  = (hi << (b2 + 1)) | (mid << (b1 + 1)) | lo | (1 << cb);
        int idx2 = idx | (1 << tb);
        float2 t0 = amp[idx], t1 = amp[idx2];
        amp[idx] = t1; amp[idx2] = t0;
    }
    __syncthreads();
}

// Rot(phi, theta, omega) = RZ(omega) RY(theta) RZ(phi) matrices for layer l
__device__ __forceinline__ void prep_gm(float2 (*gm)[4], const float* w, int l) {
    int t = threadIdx.x;
    if (t < NW) {
        const float* ww = w + (l * NW + t) * 3;
        float phi = ww[0], th = ww[1], om = ww[2];
        float ct, st;  sincosf(0.5f * th, &st, &ct);
        float ap = 0.5f * (phi + om), am = 0.5f * (phi - om);
        float cap, sap; sincosf(ap, &sap, &cap);
        float cam, sam; sincosf(am, &sam, &cam);
        gm[t][0] = make_float2( cap * ct, -sap * ct);
        gm[t][1] = make_float2(-cam * st, -sam * st);
        gm[t][2] = make_float2( cam * st, -sam * st);
        gm[t][3] = make_float2( cap * ct,  sap * ct);
    }
}

template<int L>
__global__ __launch_bounds__(BLK)
void k_pass1(const float* __restrict__ x, const float* __restrict__ w,
             float2* __restrict__ psi) {
    constexpr int r  = L + 1;
    constexpr int f1 = 12 - L, f2 = 11 - L;   // fixed (chunk) bits, adjacent
    __shared__ float2 amp[CHUNK];
    __shared__ float2 gm[NW][4];
    __shared__ float  ec[NW], es[NW];

    const int b = blockIdx.x >> 2, c = blockIdx.x & 3;
    const int tid = threadIdx.x;
    float2* g = psi + ((size_t)b << 16);

    prep_gm(gm, w, L);
    if (L == 0 && tid < NW) {
        float a = 0.5f * x[b * NW + tid];
        ec[tid] = cosf(a); es[tid] = sinf(a);
    }
    __syncthreads();

    if (L == 0) {
        // AngleEmbedding product state: amp(s) = prod_w (bit ? sin : cos)
        for (int it = 0; it < CHUNK / BLK; ++it) {
            int u = tid + it * BLK;
            int s = expand14(u, f1, f2, c);
            float prod = 1.0f;
#pragma unroll
            for (int wq = 0; wq < NW; ++wq)
                prod *= ((s >> (15 - wq)) & 1) ? es[wq] : ec[wq];
            amp[u] = make_float2(prod, 0.0f);
        }
    } else {
        for (int it = 0; it < CHUNK / 2 / BLK; ++it) {     // float4 loads
            int v = tid + it * BLK;
            int s = expand14(2 * v, f1, f2, c);
            reinterpret_cast<float4*>(amp)[v] =
                *reinterpret_cast<const float4*>(g + s);
        }
    }
    __syncthreads();

    // H2(L-1): high CNOTs of previous layer
    if (L >= 1) {
        constexpr int rp = L;     // r of layer L-1
        if (rp == 1) {
            cnot_lds(amp, localbit(0, f1, f2), localbit(15, f1, f2));          // CNOT(15,0)
        } else {
            cnot_lds(amp, localbit(rp - 1, f1, f2), localbit(15, f1, f2));     // CNOT(16-rp,0)
            cnot_lds(amp, localbit(rp - 2, f1, f2), localbit(14, f1, f2));     // CNOT(17-rp,1)
        }
    }

    // Rot on wires 0,1,r,r+1 (dedupe for r==1)
    {
        auto do_rot = [&](int wq) {
            int lb = localbit(15 - wq, f1, f2);
            rot_lds(amp, lb, gm[wq][0], gm[wq][1], gm[wq][2], gm[wq][3]);
        };
        do_rot(0); do_rot(1);
        if (r > 1) do_rot(r);
        do_rot(r + 1);
    }

    // H1: CNOT(0,r), CNOT(1,r+1)
    cnot_lds(amp, localbit(15, f1, f2), localbit(15 - r, f1, f2));
    cnot_lds(amp, localbit(14, f1, f2), localbit(15 - (r + 1), f1, f2));

    for (int it = 0; it < CHUNK / 2 / BLK; ++it) {         // float4 stores
        int v = tid + it * BLK;
        int s = expand14(2 * v, f1, f2, c);
        *reinterpret_cast<float4*>(g + s) = reinterpret_cast<float4*>(amp)[v];
    }
}

template<int L>
__global__ __launch_bounds__(BLK)
void k_pass2(const float* __restrict__ w, float2* __restrict__ psi) {
    constexpr int r = L + 1;
    __shared__ float2 amp[CHUNK];
    __shared__ float2 gm[NW][4];

    const int b = blockIdx.x >> 2, c = blockIdx.x & 3;
    const int tid = threadIdx.x;
    float2* g = psi + ((size_t)b << 16) + ((size_t)c << 14);  // fixed bits {15,14}

    prep_gm(gm, w, L);
    __syncthreads();
    for (int it = 0; it < CHUNK / 2 / BLK; ++it) {
        int v = tid + it * BLK;
        reinterpret_cast<float4*>(amp)[v] =
            reinterpret_cast<const float4*>(g)[v];
    }
    __syncthreads();

    // Rot on wires 2..15 except {r, r+1}; local bit = 15 - wq (fixed {15,14})
#pragma unroll
    for (int wq = 2; wq < NW; ++wq) {
        if (wq == r || wq == r + 1) continue;
        rot_lds(amp, 15 - wq, gm[wq][0], gm[wq][1], gm[wq][2], gm[wq][3]);
    }
    // ring CNOTs not touching wires 0,1, ascending i
#pragma unroll
    for (int i = 2; i < NW; ++i) {
        int j = (i + r) & 15;
        if (j == 0 || j == 1) continue;
        cnot_lds(amp, 15 - i, 15 - j);
    }

    for (int it = 0; it < CHUNK / 2 / BLK; ++it) {
        int v = tid + it * BLK;
        reinterpret_cast<float4*>(g)[v] = reinterpret_cast<float4*>(amp)[v];
    }
}

__global__ __launch_bounds__(BLK)
void k_pass3(float2* __restrict__ psi, float* __restrict__ out) {
    constexpr int f1 = 12, f2 = 11;   // avoid wires {0,1,10,11} = bits {15,14,5,4}
    __shared__ float2 amp[CHUNK];
    __shared__ float  acc[NW];

    const int b = blockIdx.x >> 2, c = blockIdx.x & 3;
    const int tid = threadIdx.x;
    float2* g = psi + ((size_t)b << 16);

    for (int it = 0; it < CHUNK / 2 / BLK; ++it) {
        int v = tid + it * BLK;
        int s = expand14(2 * v, f1, f2, c);
        reinterpret_cast<float4*>(amp)[v] =
            *reinterpret_cast<const float4*>(g + s);
    }
    __syncthreads();

    // H2(5): r=6 -> CNOT(10,0), CNOT(11,1)
    cnot_lds(amp, localbit(5, f1, f2), localbit(15, f1, f2));
    cnot_lds(amp, localbit(4, f1, f2), localbit(14, f1, f2));

    float z[NW];
#pragma unroll
    for (int i = 0; i < NW; ++i) z[i] = 0.0f;

    for (int it = 0; it < CHUNK / BLK; ++it) {
        int u = tid + it * BLK;
        int s = expand14(u, f1, f2, c);
        float2 a = amp[u];
        float p = a.x * a.x + a.y * a.y;
#pragma unroll
        for (int i = 0; i < NW; ++i)
            z[i] += ((s >> (15 - i)) & 1) ? -p : p;
    }

    if (tid < NW) acc[tid] = 0.0f;
    __syncthreads();
#pragma unroll
    for (int i = 0; i < NW; ++i) {
        float v = z[i];
        for (int off = 32; off > 0; off >>= 1)
            v += __shfl_down(v, off, 64);
        if ((tid & 63) == 0) atomicAdd(&acc[i], v);
    }
    __syncthreads();
    if (tid < NW) atomicAdd(&out[b * NW + tid], acc[tid]);
}

extern "C" void kernel_launch(void* const* d_in, const int* in_sizes, int n_in,
                              void* d_out, int out_size, void* d_ws, size_t ws_size,
                              hipStream_t stream) {
    const float* x = (const float*)d_in[0];   // (B, 16) float32
    const float* w = (const float*)d_in[1];   // (6, 16, 3) float32
    float* out = (float*)d_out;               // (B, 16) float32
    float2* psi = (float2*)d_ws;              // B * 65536 * 8 B = 64 MiB

    const int batch = in_sizes[0] / NW;
    const int grid  = batch * 4;              // 4 chunks per batch

    hipMemsetAsync(d_out, 0, (size_t)out_size * sizeof(float), stream);

    k_pass1<0><<<grid, BLK, 0, stream>>>(x, w, psi);
    k_pass2<0><<<grid, BLK, 0, stream>>>(w, psi);
    k_pass1<1><<<grid, BLK, 0, stream>>>(x, w, psi);
    k_pass2<1><<<grid, BLK, 0, stream>>>(w, psi);
    k_pass1<2><<<grid, BLK, 0, stream>>>(x, w, psi);
    k_pass2<2><<<grid, BLK, 0, stream>>>(w, psi);
    k_pass1<3><<<grid, BLK, 0, stream>>>(x, w, psi);
    k_pass2<3><<<grid, BLK, 0, stream>>>(w, psi);
    k_pass1<4><<<grid, BLK, 0, stream>>>(x, w, psi);
    k_pass2<4><<<grid, BLK, 0, stream>>>(w, psi);
    k_pass1<5><<<grid, BLK, 0, stream>>>(x, w, psi);
    k_pass2<5><<<grid, BLK, 0, stream>>>(w, psi);
    k_pass3<<<grid, BLK, 0, stream>>>(psi, out);
}